// Round 1
// baseline (214.723 us; speedup 1.0000x reference)
//
#include <hip/hip_runtime.h>

// Problem constants
#define INC    256
#define HIN    56
#define WIN    56
#define HOUT   19
#define WOUT   58
#define KTOT   768          // 24 MFMA K-steps; 3 chunks of 8 (one kh row each)

typedef short frag8 __attribute__((ext_vector_type(8)));   // 8 bf16 bits (4 VGPRs)
typedef float f32x4 __attribute__((ext_vector_type(4)));   // MFMA accumulator
typedef float f4    __attribute__((ext_vector_type(4)));
typedef f4 f4a __attribute__((aligned(4)));                // 4B-aligned float4 (dwordx4 ok)

static __device__ __forceinline__ unsigned short f2bf(float f) {
    unsigned u = __float_as_uint(f);
    u += 0x7fffu + ((u >> 16) & 1u);      // round-to-nearest-even
    return (unsigned short)(u >> 16);
}

// ---------------------------------------------------------------------------
// prep_weff: unchanged (fold sparse einsum into dense conv weights in MFMA
// A-fragment-linear order). ~5 us, not the bottleneck.
// ---------------------------------------------------------------------------
__global__ __launch_bounds__(256) void prep_weff(
    const float* __restrict__ lego,    // [64][64][3]
    const float* __restrict__ coefs,   // [4][256][64]
    const float* __restrict__ comb,    // [4][256][64]
    unsigned short* __restrict__ Asw)  // [16][24][64][8] bf16 bits
{
    __shared__ int   idxS[4];
    __shared__ float cofS[4];
    const int t  = threadIdx.x;
    const int kx = blockIdx.x;         // 0..2
    const int o  = blockIdx.y;         // 0..255
    const int wv = t >> 6, l = t & 63;

    float v  = comb[(wv * 256 + o) * 64 + l];
    int   bi = l;
    #pragma unroll
    for (int off = 32; off >= 1; off >>= 1) {
        float ov = __shfl_xor(v, off, 64);
        int   oi = __shfl_xor(bi, off, 64);
        if (ov > v || (ov == v && oi < bi)) { v = ov; bi = oi; }
    }
    if (l == 0) {
        idxS[wv] = bi;
        cofS[wv] = coefs[(wv * 256 + o) * 64 + bi];
    }
    __syncthreads();

    const int k  = kx * 256 + t;       // 0..767
    const int kh = k >> 8, c = k & 255;
    const int i  = c >> 6, cl = c & 63;
    float w = cofS[i] * lego[idxS[i] * 192 + cl * 3 + kh];

    const int o_tile = o >> 4, m = o & 15;
    const int ks = k >> 5, kc = (k >> 3) & 3, j = k & 7;
    Asw[((((size_t)o_tile * 24 + ks) * 64) + kc * 16 + m) * 8 + j] = f2bf(w);
}

// ---------------------------------------------------------------------------
// R5 restructure rationale (from rocprof): MfmaUtil 7.6 / VALU 10.8 / HBM 25%
// with FETCH exactly minimal -> latency-bound staging (stage and MFMA were
// fully serialized by syncthreads; ~1 dword in flight per lane).
// Changes:
//  * 3 K-chunks of 256 (= one kh input row each); per chunk each thread does
//    8 x float4 loads (16B/lane, 8x128B segments/wave-instr) instead of 48
//    scalar dwords.
//  * LDS double buffer 2x16KB + async-stage split: loads for chunk c+1 are
//    ISSUED before the MFMA pass over chunk c; the ds_writes (vmcnt-gated)
//    sink below the MFMAs. Only chunk 0's latency is exposed.
//  * float4 staging makes lo jump by 4 per lane -> XOR bank swizzle
//    slot = kc*16 + (lo ^ kc) on write, (l ^ (l>>4)) on read; both sides
//    uniform 8 lanes per 4-bank group (b128-ideal, 0 conflicts expected).
//  * __launch_bounds__(256,4): 128-VGPR cap for acc(32,AGPR) + 32 in-flight
//    floats + A depth-1 prefetch. 4 blocks/CU (LDS allows 5).
// ---------------------------------------------------------------------------

static __device__ __forceinline__ void load_rows(
    const float* __restrict__ xr,   // = xb + chb*HW + row*WIN + col4 (maybe OOB, not deref'd unless ok)
    bool rok, int col4, f4 v[8])
{
    const size_t HW = (size_t)HIN * WIN;
    const bool allok = rok && (col4 >= 0) && (col4 + 3 < WIN);
    if (allok) {
        #pragma unroll
        for (int j = 0; j < 8; ++j)
            v[j] = *(const f4a*)(xr + j * HW);
    } else {
        #pragma unroll
        for (int j = 0; j < 8; ++j) {
            #pragma unroll
            for (int e = 0; e < 4; ++e) {
                int c = col4 + e;
                v[j][e] = (rok && (unsigned)c < (unsigned)WIN) ? xr[j * HW + e] : 0.f;
            }
        }
    }
}

static __device__ __forceinline__ void write_chunk(
    unsigned short* __restrict__ bsb,  // &buf[(((ksl*2+wt)*64) + kc*16 + lb)*8]
    int kc, const f4 v[8])
{
    #pragma unroll
    for (int i = 0; i < 4; ++i) {
        union { frag8 f; unsigned short u[8]; } pk;
        #pragma unroll
        for (int j = 0; j < 8; ++j) pk.u[j] = f2bf(v[j][i]);
        *(frag8*)(bsb + (i ^ kc) * 8) = pk.f;   // XOR swizzle vs write conflicts
    }
}

static __device__ __forceinline__ void mfma_chunk(
    const frag8* __restrict__ Af,   // lane-resolved A base
    const frag8* __restrict__ Xf,   // lane-resolved (swizzled) B base for this buffer
    int ksb, f32x4 (&acc)[4][2])
{
    frag8 a[4], an[4];
    #pragma unroll
    for (int ot = 0; ot < 4; ++ot) a[ot] = Af[(ot * 24 + ksb) * 64];
    #pragma unroll
    for (int ks = 0; ks < 8; ++ks) {
        if (ks < 7) {          // depth-1 A prefetch (global/L2, ~200cy)
            #pragma unroll
            for (int ot = 0; ot < 4; ++ot) an[ot] = Af[(ot * 24 + ksb + ks + 1) * 64];
        }
        frag8 b0 = Xf[(ks * 2) * 64];
        frag8 b1 = Xf[(ks * 2 + 1) * 64];
        #pragma unroll
        for (int ot = 0; ot < 4; ++ot) {
            acc[ot][0] = __builtin_amdgcn_mfma_f32_16x16x32_bf16(a[ot], b0, acc[ot][0], 0, 0, 0);
            acc[ot][1] = __builtin_amdgcn_mfma_f32_16x16x32_bf16(a[ot], b1, acc[ot][1], 0, 0, 0);
        }
        if (ks < 7) {
            #pragma unroll
            for (int ot = 0; ot < 4; ++ot) a[ot] = an[ot];
        }
    }
}

__global__ __launch_bounds__(256, 4) void conv_mfma(
    const float* __restrict__ x,             // [32][256][56][56]
    const unsigned short* __restrict__ Asw,  // [16][24][64][8]
    float* __restrict__ out)                 // [32][256][19][58]
{
    __shared__ unsigned short Xs[2][8 * 2 * 64 * 8];   // 2 x 16 KB double buffer

    const int t  = threadIdx.x;
    const int wh = blockIdx.x;               // 0/1 w-half
    const int h  = blockIdx.y;               // 0..18
    const int b  = blockIdx.z;               // 0..31

    const int l  = t & 63;
    const int lo = l & 15;
    const int hi = l >> 4;
    const int wv = t >> 6;

    f32x4 acc[4][2];
    #pragma unroll
    for (int ot = 0; ot < 4; ++ot)
        #pragma unroll
        for (int nt = 0; nt < 2; ++nt)
            acc[ot][nt] = (f32x4){0.f, 0.f, 0.f, 0.f};

    // ---- staging mapping: thread = (pg = channel-oct 0..31, cg = colgrp 0..7)
    const int cg   = t & 7;
    const int pg   = t >> 3;
    const int chb  = pg * 8;                 // base channel; j adds 0..7
    const int col4 = wh * 32 - 1 + cg * 4;   // first input col of this group
    const int rowbase = 3 * h - 1;
    const size_t HW = (size_t)HIN * WIN;
    const float* xpt = x + (size_t)b * (INC * HIN * WIN) + (size_t)chb * HW;

    const int ksl = pg >> 2, kc = pg & 3, wt = cg >> 2, lb = (cg & 3) * 4;
    const int wslot = (((ksl * 2 + wt) * 64) + kc * 16 + lb) * 8;

    const frag8* Af = (const frag8*)Asw + ((size_t)(wv * 4) * 24) * 64 + l;
    const int xfo = l ^ (l >> 4);            // swizzled B-frag lane offset
    const frag8* Xf0 = (const frag8*)Xs[0] + xfo;
    const frag8* Xf1 = (const frag8*)Xs[1] + xfo;

    f4 v[8];

    // ---- chunk 0 (kh=0, row = 3h-1): latency exposed (nothing to hide under)
    load_rows(xpt + (ptrdiff_t)rowbase * WIN + col4, (unsigned)rowbase < (unsigned)HIN, col4, v);
    write_chunk(&Xs[0][wslot], kc, v);
    // issue chunk-1 loads before the barrier: in flight across barrier + MFMA
    load_rows(xpt + (ptrdiff_t)(rowbase + 1) * WIN + col4, (unsigned)(rowbase + 1) < (unsigned)HIN, col4, v);
    __syncthreads();                         // (A) buf0 ready

    mfma_chunk(Af, Xf0, 0, acc);             // chunk 0 compute, hides c1 loads
    write_chunk(&Xs[1][wslot], kc, v);       // vmcnt-gated, sinks after MFMAs
    load_rows(xpt + (ptrdiff_t)(rowbase + 2) * WIN + col4, (unsigned)(rowbase + 2) < (unsigned)HIN, col4, v);
    __syncthreads();                         // (B) buf1 ready; buf0 reads done

    mfma_chunk(Af, Xf1, 8, acc);             // chunk 1 compute, hides c2 loads
    write_chunk(&Xs[0][wslot], kc, v);
    __syncthreads();                         // (C) buf0 ready (chunk 2)

    mfma_chunk(Af, Xf0, 16, acc);            // chunk 2 compute

    // ---- store: D col = lo (w), row = hi*4 + r (o within 16-tile) ----
    const int wb = wh * 32;
    const int obase = wv * 64;
    #pragma unroll
    for (int ot = 0; ot < 4; ++ot) {
        #pragma unroll
        for (int nt = 0; nt < 2; ++nt) {
            int wcol = wb + nt * 16 + lo;
            if (wcol < WOUT) {
                #pragma unroll
                for (int r = 0; r < 4; ++r) {
                    int o = obase + ot * 16 + hi * 4 + r;
                    out[((size_t)(b * 256 + o) * HOUT + h) * WOUT + wcol] = acc[ot][nt][r];
                }
            }
        }
    }
}

extern "C" void kernel_launch(void* const* d_in, const int* in_sizes, int n_in,
                              void* d_out, int out_size, void* d_ws, size_t ws_size,
                              hipStream_t stream) {
    const float* x     = (const float*)d_in[0];   // (32,256,56,56)
    const float* lego  = (const float*)d_in[1];   // (64,64,3,1)
    const float* coefs = (const float*)d_in[2];   // (4,256,64,1,1)
    const float* comb  = (const float*)d_in[3];   // (4,256,64,1,1)
    float* out = (float*)d_out;                   // (32,256,19,58)

    unsigned short* Asw = (unsigned short*)d_ws;  // 196,608 bf16 = 384 KB

    prep_weff<<<dim3(3, 256), 256, 0, stream>>>(lego, coefs, comb, Asw);
    conv_mfma<<<dim3(2, HOUT, 32), 256, 0, stream>>>(x, Asw, out);
}

// Round 2
// 193.845 us; speedup vs baseline: 1.1077x; 1.1077x over previous
//
#include <hip/hip_runtime.h>

// Problem constants
#define INC    256
#define HIN    56
#define WIN    56
#define HOUT   19
#define WOUT   58
#define HW     3136          // HIN*WIN

typedef short frag8 __attribute__((ext_vector_type(8)));   // 8 bf16 bits (4 VGPRs)
typedef float f32x4 __attribute__((ext_vector_type(4)));   // MFMA accumulator
typedef float f4    __attribute__((ext_vector_type(4)));

static __device__ __forceinline__ unsigned short f2bf(float f) {
    unsigned u = __float_as_uint(f);
    u += 0x7fffu + ((u >> 16) & 1u);      // round-to-nearest-even
    return (unsigned short)(u >> 16);
}

// f32 pair -> packed 2x bf16 (RNE), lo16 = a, hi16 = b
static __device__ __forceinline__ unsigned cvtpk(float a, float b) {
    unsigned r;
    asm("v_cvt_pk_bf16_f32 %0, %1, %2" : "=v"(r) : "v"(a), "v"(b));
    return r;
}

#define VMCNT(n) asm volatile("s_waitcnt vmcnt(" #n ")" ::: "memory")
#define FENCE()  asm volatile("" ::: "memory")

// ---------------------------------------------------------------------------
// prep_weff: unchanged. Folds sparse einsum into dense conv weights in MFMA
// A-fragment-linear order: Asw[o_tile 16][ks 24][lane 64][j 8] bf16.
// ---------------------------------------------------------------------------
__global__ __launch_bounds__(256) void prep_weff(
    const float* __restrict__ lego,    // [64][64][3]
    const float* __restrict__ coefs,   // [4][256][64]
    const float* __restrict__ comb,    // [4][256][64]
    unsigned short* __restrict__ Asw)
{
    __shared__ int   idxS[4];
    __shared__ float cofS[4];
    const int t  = threadIdx.x;
    const int kx = blockIdx.x;         // 0..2
    const int o  = blockIdx.y;         // 0..255
    const int wv = t >> 6, l = t & 63;

    float v  = comb[(wv * 256 + o) * 64 + l];
    int   bi = l;
    #pragma unroll
    for (int off = 32; off >= 1; off >>= 1) {
        float ov = __shfl_xor(v, off, 64);
        int   oi = __shfl_xor(bi, off, 64);
        if (ov > v || (ov == v && oi < bi)) { v = ov; bi = oi; }
    }
    if (l == 0) {
        idxS[wv] = bi;
        cofS[wv] = coefs[(wv * 256 + o) * 64 + bi];
    }
    __syncthreads();

    const int k  = kx * 256 + t;       // 0..767
    const int kh = k >> 8, c = k & 255;
    const int i  = c >> 6, cl = c & 63;
    float w = cofS[i] * lego[idxS[i] * 192 + cl * 3 + kh];

    const int o_tile = o >> 4, m = o & 15;
    const int ks = k >> 5, kc = (k >> 3) & 3, j = k & 7;
    Asw[((((size_t)o_tile * 24 + ks) * 64) + kc * 16 + m) * 8 + j] = f2bf(w);
}

// ---------------------------------------------------------------------------
// R6 conv: one block per (b,h), 256 threads (4 waves), out tile 256o x 64w.
// Key insight: out cols 0 and 57 are identically ZERO (kw=1 + w-padding), so
// real outputs are cols 1..56 <- input cols 0..55: staging is 16B-ALIGNED.
// Staging: global_load_lds (f32, no VGPR round trip, fire-and-forget).
//   12 chunks (kh 0..2 x 64-ch quarter), 3 x 16KB LDS buffers, depth-2
//   prefetch, raw s_barrier + counted vmcnt (NO __syncthreads: it drains
//   vmcnt(0) and serializes the pipe — the R4/R5 failure).
// LDS layout [ch64][slot64] f32, ch stride 256B; col c of channel ch stored
// at slot (c&32)|((c+8*kc)&31), kc=(ch>>3)&3 — applied by pre-swizzling the
// GLOBAL source address (gll dest must stay lane-linear). Read-side banks:
// 16-col windows shifted 8 per kc => uniform 2-way = free.
// bf16 conversion at fragment-assembly (v_cvt_pk_bf16_f32), VALU co-issues
// with MFMA; ~2x redundant cvt is far under the HBM floor.
// ---------------------------------------------------------------------------
__global__ __launch_bounds__(256, 3) void conv_mfma(
    const float* __restrict__ x,             // [32][256][56][56]
    const unsigned short* __restrict__ Asw,  // [16][24][64][8]
    float* __restrict__ out)                 // [32][256][19][58]
{
    __shared__ float Xs[3][4096];            // 3 x 16KB staging buffers

    const int t  = threadIdx.x;
    const int h  = blockIdx.x;               // 0..18
    const int b  = blockIdx.y;               // 0..31
    const int l  = t & 63;
    const int lo = l & 15;
    const int hi = l >> 4;                   // = kc for A/B fragment lanes
    const int wv = t >> 6;
    const int kc = hi;

    // ---- B-read per-lane constants: addr = buf + kc*2048 + slotb[wt]
    //      + (ksl*8192 + j*256) [immediate]
    int slotb[4];
    #pragma unroll
    for (int wt = 0; wt < 4; ++wt) {
        int c    = wt * 16 + lo;
        int slot = (c & 32) | ((c + 8 * kc) & 31);
        slotb[wt] = slot * 4;
    }
    const int bko = kc * 2048;

    // ---- staging per-lane constants (lane-linear LDS dest, swizzled source)
    const int gs = l & 15, chof = l >> 4;
    unsigned goff[4];                        // global float offset per instr
    int      ldsu[4];                        // wave-uniform LDS byte base
    #pragma unroll
    for (int i = 0; i < 4; ++i) {
        int I    = wv * 4 + i;               // instr 0..15 within chunk
        int chl  = I * 4 + chof;             // channel-local 0..63
        int kcs  = (chl >> 3) & 3;
        int half = gs >> 3, gsw = gs & 7;
        int g    = (gsw - 2 * kcs) & 7;      // inverse of read-side rotation
        int col  = half * 32 + g * 4;
        if (col >= WIN) col = 0;             // OOB cols 56..63: safe garbage,
                                             // feeds only discarded outputs
        goff[i] = (unsigned)chl * HW + col;
        ldsu[i] = I * 1024;                  // HW adds lane*16
    }

    const float* xb = x + (size_t)b * (INC * HW);
    const frag8* Af = (const frag8*)Asw + (size_t)(wv * 4) * 24 * 64 + l;
    char* XsB = (char*)&Xs[0][0];

    f32x4 acc[4][4];
    #pragma unroll
    for (int ot = 0; ot < 4; ++ot)
        #pragma unroll
        for (int wt = 0; wt < 4; ++wt)
            acc[ot][wt] = (f32x4){0.f, 0.f, 0.f, 0.f};

    // stage chunk q into buf q%3: 4 gll instrs/wave (or ds_write zeros for
    // the padded row h==0,kh==0; block-uniform branch, no barrier inside)
    auto STAGE = [&](int q) {
        const int kh = q >> 2, cq = q & 3;
        const int row = 3 * h - 1 + kh;
        const int bufo = (q % 3) * 16384;
        if (row < 0) {                       // only h==0, kh==0
            f4 z = (f4){0.f, 0.f, 0.f, 0.f};
            #pragma unroll
            for (int i = 0; i < 4; ++i)
                *(f4*)(XsB + bufo + ldsu[i] + l * 16) = z;
            asm volatile("s_waitcnt lgkmcnt(0)" ::: "memory");
        } else {
            const float* rp = xb + (size_t)cq * 64 * HW + row * WIN;
            #pragma unroll
            for (int i = 0; i < 4; ++i) {
                __builtin_amdgcn_global_load_lds(
                    (const __attribute__((address_space(1))) void*)(rp + goff[i]),
                    (__attribute__((address_space(3))) void*)(XsB + bufo + ldsu[i]),
                    16, 0, 0);
            }
        }
    };

    STAGE(0);
    STAGE(1);

    #pragma unroll
    for (int q = 0; q < 12; ++q) {
        if (q + 2 < 12) STAGE(q + 2);        // depth-2 prefetch, issued first

        // A fragments for this chunk (L2-hot, compiler-managed waits; their
        // in-order retire also guarantees stage(q) completed — FIFO vmcnt)
        frag8 a[4][2];
        #pragma unroll
        for (int ot = 0; ot < 4; ++ot)
            #pragma unroll
            for (int ksl = 0; ksl < 2; ++ksl)
                a[ot][ksl] = Af[(ot * 24 + q * 2 + ksl) * 64];

        // counted wait: steady outstanding = s(q+1)+s(q+2)+A(q) = 16
        if (q < 10)       { VMCNT(16); }
        else if (q == 10) { VMCNT(12); }
        else              { VMCNT(8);  }
        __builtin_amdgcn_s_barrier();        // buf q%3 ready for all waves
        FENCE();

        const char* bb = XsB + (q % 3) * 16384 + bko;
        #pragma unroll
        for (int ksl = 0; ksl < 2; ++ksl) {
            #pragma unroll
            for (int wt = 0; wt < 4; ++wt) {
                float f0 = *(const float*)(bb + ksl * 8192 + 0 * 256 + slotb[wt]);
                float f1 = *(const float*)(bb + ksl * 8192 + 1 * 256 + slotb[wt]);
                float f2 = *(const float*)(bb + ksl * 8192 + 2 * 256 + slotb[wt]);
                float f3 = *(const float*)(bb + ksl * 8192 + 3 * 256 + slotb[wt]);
                float f4_ = *(const float*)(bb + ksl * 8192 + 4 * 256 + slotb[wt]);
                float f5 = *(const float*)(bb + ksl * 8192 + 5 * 256 + slotb[wt]);
                float f6 = *(const float*)(bb + ksl * 8192 + 6 * 256 + slotb[wt]);
                float f7 = *(const float*)(bb + ksl * 8192 + 7 * 256 + slotb[wt]);
                union { frag8 fr; unsigned u[4]; } B;
                B.u[0] = cvtpk(f0, f1);
                B.u[1] = cvtpk(f2, f3);
                B.u[2] = cvtpk(f4_, f5);
                B.u[3] = cvtpk(f6, f7);
                #pragma unroll
                for (int ot = 0; ot < 4; ++ot)
                    acc[ot][wt] = __builtin_amdgcn_mfma_f32_16x16x32_bf16(
                        a[ot][ksl], B.fr, acc[ot][wt], 0, 0, 0);
            }
        }
        FENCE();
        __builtin_amdgcn_s_barrier();        // all reads of buf q%3 done
    }

    // ---- store: out col = n+1 for n=0..55; cols 0 and 57 are exact zeros
    #pragma unroll
    for (int ot = 0; ot < 4; ++ot) {
        #pragma unroll
        for (int r = 0; r < 4; ++r) {
            int o = wv * 64 + ot * 16 + hi * 4 + r;
            float* orow = out + ((size_t)(b * 256 + o) * HOUT + h) * WOUT;
            #pragma unroll
            for (int wt = 0; wt < 4; ++wt) {
                int n = wt * 16 + lo;
                if (n < 56) orow[n + 1] = acc[ot][wt][r];
            }
            if (lo == 0) orow[0]  = 0.f;
            if (lo == 1) orow[57] = 0.f;
        }
    }
}

extern "C" void kernel_launch(void* const* d_in, const int* in_sizes, int n_in,
                              void* d_out, int out_size, void* d_ws, size_t ws_size,
                              hipStream_t stream) {
    const float* x     = (const float*)d_in[0];   // (32,256,56,56)
    const float* lego  = (const float*)d_in[1];   // (64,64,3,1)
    const float* coefs = (const float*)d_in[2];   // (4,256,64,1,1)
    const float* comb  = (const float*)d_in[3];   // (4,256,64,1,1)
    float* out = (float*)d_out;                   // (32,256,19,58)

    unsigned short* Asw = (unsigned short*)d_ws;  // 196,608 bf16 = 384 KB

    prep_weff<<<dim3(3, 256), 256, 0, stream>>>(lego, coefs, comb, Asw);
    conv_mfma<<<dim3(HOUT, 32), 256, 0, stream>>>(x, Asw, out);
}